// Round 14
// baseline (131.400 us; speedup 1.0000x reference)
//
#include <hip/hip_runtime.h>

// DIAGNOSTIC ROUND: kernels identical to R13; k_final launched 5x (idempotent)
// to measure t_final via dur_us arithmetic: t_final ~ (dur - 55)/4.
//
// ConvDistanceTransform closed form:
//   D = Chebyshev distance transform of seeds (exact, separable)
//   i = (D-1)/3 ; out = 3.5*i - 0.35*log( sum_{q in 7x7, D(q)<=3i} exp(-|p-q|_2/0.35) )

typedef unsigned short u16x4 __attribute__((ext_vector_type(4)));

#define BIGV (1 << 20)
#define ROWB 272  // u8 d1 row: 8 guard + 256 + 8 guard
#define CHB (256 * ROWB)

// ---------- Kernel A: per-row 1-D distance, wave-per-row register scans ----------
__global__ __launch_bounds__(256) void k_rowdist(const float* __restrict__ img,
                                                 unsigned char* __restrict__ d1) {
  const int lane = threadIdx.x & 63;
  const int wv = threadIdx.x >> 6;
  const int row = blockIdx.x * 4 + wv;  // ch*256 + y
  const int x0 = lane * 4;

  const float4 v = *reinterpret_cast<const float4*>(&img[(size_t)row * 256 + x0]);

  int c0 = (v.x != 0.0f) ? -x0 : BIGV;
  int c1 = (v.y != 0.0f) ? -(x0 + 1) : BIGV;
  int c2 = (v.z != 0.0f) ? -(x0 + 2) : BIGV;
  int c3 = (v.w != 0.0f) ? -(x0 + 3) : BIGV;
  const int p0 = c0;
  const int p1 = min(c1, p0);
  const int p2 = min(c2, p1);
  const int p3 = min(c3, p2);
  int incl = p3;
#pragma unroll
  for (int off = 1; off < 64; off <<= 1) {
    int o = __shfl_up(incl, off, 64);
    if (lane >= off) incl = min(incl, o);
  }
  int excl = __shfl_up(incl, 1, 64);
  if (lane == 0) excl = BIGV;
  const int df0 = x0 + min(p0, excl);
  const int df1 = x0 + 1 + min(p1, excl);
  const int df2 = x0 + 2 + min(p2, excl);
  const int df3 = x0 + 3 + min(p3, excl);

  int g0 = (v.x != 0.0f) ? x0 : BIGV;
  int g1 = (v.y != 0.0f) ? (x0 + 1) : BIGV;
  int g2 = (v.z != 0.0f) ? (x0 + 2) : BIGV;
  int g3 = (v.w != 0.0f) ? (x0 + 3) : BIGV;
  const int q3 = g3;
  const int q2 = min(g2, q3);
  const int q1 = min(g1, q2);
  const int q0 = min(g0, q1);
  int incl2 = q0;
#pragma unroll
  for (int off = 1; off < 64; off <<= 1) {
    int o = __shfl_down(incl2, off, 64);
    if (lane < 64 - off) incl2 = min(incl2, o);
  }
  int excl2 = __shfl_down(incl2, 1, 64);
  if (lane == 63) excl2 = BIGV;
  const int db0 = min(q0, excl2) - x0;
  const int db1 = min(q1, excl2) - (x0 + 1);
  const int db2 = min(q2, excl2) - (x0 + 2);
  const int db3 = min(q3, excl2) - (x0 + 3);

  const unsigned int d0 = (unsigned int)min(min(df0, db0), 127);
  const unsigned int d1v = (unsigned int)min(min(df1, db1), 127);
  const unsigned int d2 = (unsigned int)min(min(df2, db2), 127);
  const unsigned int d3 = (unsigned int)min(min(df3, db3), 127);
  const int ch = row >> 8, y = row & 255;
  const size_t base = (size_t)ch * CHB + (size_t)y * ROWB;
  *reinterpret_cast<unsigned int*>(&d1[base + 8 + x0]) =
      d0 | (d1v << 8) | (d2 << 16) | (d3 << 24);
  if (lane < 2)
    *reinterpret_cast<unsigned int*>(&d1[base + lane * 4]) = 0u;
  else if (lane >= 62)
    *reinterpret_cast<unsigned int*>(&d1[base + 264 + (lane - 62) * 4]) = 0u;
}

#define LDQ(off) (*reinterpret_cast<const u16x4*>(&s1[(off)]))
#define EMIN __builtin_elementwise_min
#define EMAX __builtin_elementwise_max

#define PFX(OUT, a0, a1, a2, a3, a4, a5, a6, a7, a8, a9, a10, a11, a12, a13,    \
            a14, a15, a16)                                                      \
  u16x4 OUT = EMIN(                                                             \
      EMIN(EMIN(EMIN(EMAX(a7, K1), EMAX(a9, K1)),                               \
                EMIN(EMAX(a6, K2), EMAX(a10, K2))),                             \
           EMIN(EMIN(EMAX(a5, K3), EMAX(a11, K3)),                              \
                EMIN(EMAX(a4, K4), EMAX(a12, K4)))),                            \
      EMIN(EMIN(EMIN(EMAX(a3, K5), EMAX(a13, K5)),                              \
                EMIN(EMAX(a2, K6), EMAX(a14, K6))),                             \
           EMIN(EMIN(EMAX(a1, K7), EMAX(a15, K7)),                              \
                EMIN(EMAX(a0, K8), EMAX(a16, K8)))));                           \
  OUT = EMIN(OUT, a8)

#define TUP(OUT, b3, b2, b1, b0, d0, d1, d2, d3)                                \
  OUT = EMIN(OUT, EMIN(EMIN(EMIN(EMAX(b3, Kc0), EMAX(b2, Kc1)),                 \
                            EMIN(EMAX(b1, Kc2), EMAX(b0, Kc3))),                \
                       EMIN(EMIN(EMAX(d0, Kc0), EMAX(d1, Kc1)),                 \
                            EMIN(EMAX(d2, Kc2), EMAX(d3, Kc3)))))

#define BMOF(MX)                                                                \
  ({                                                                            \
    const unsigned long long mb_ = __builtin_bit_cast(unsigned long long, MX);  \
    const unsigned int ml_ = (unsigned int)mb_, mh_ = (unsigned int)(mb_ >> 32);\
    max(max((int)(ml_ & 0xFFFFu), (int)(ml_ >> 16)),                            \
        max((int)(mh_ & 0xFFFFu), (int)(mh_ >> 16)));                           \
  })

// ---------- Kernel B: column min-max transform, 16-col strips -> u8 D ----------
__global__ __launch_bounds__(256) void k_coldist(const unsigned char* __restrict__ d1,
                                                 unsigned char* __restrict__ Dg) {
  const int ch = blockIdx.y;
  const int xt = blockIdx.x;  // 0..15
  const int x0 = xt * 16;
  const int tid = threadIdx.x;

  __shared__ __align__(16) unsigned char s1[279 * 40];

  if (tid < 230) {
    const int r = (tid * 6554) >> 16;  // /10
    const int c = tid - r * 10;
    const int row = (r < 11) ? r : r + 256;
    *reinterpret_cast<unsigned int*>(&s1[row * 40 + c * 4]) = 0x007F007Fu;
  }
  const unsigned char* src = d1 + (size_t)ch * CHB + 8 + x0;
#pragma unroll
  for (int it = 0; it < 4; ++it) {
    const int idx = it * 256 + tid;  // 0..1023
    const int y = idx >> 2, c = idx & 3;
    const unsigned int q = *reinterpret_cast<const unsigned int*>(&src[y * ROWB + c * 4]);
    *reinterpret_cast<unsigned int*>(&s1[(y + 11) * 40 + c * 8]) =
        __builtin_amdgcn_perm(0u, q, 0x0C010C00u);
    *reinterpret_cast<unsigned int*>(&s1[(y + 11) * 40 + c * 8 + 4]) =
        __builtin_amdgcn_perm(0u, q, 0x0C030C02u);
  }
  __syncthreads();

  if (tid < 208) {
    const u16x4 K1 = {1, 1, 1, 1}, K2 = {2, 2, 2, 2}, K3 = {3, 3, 3, 3},
                K4 = {4, 4, 4, 4}, K5 = {5, 5, 5, 5}, K6 = {6, 6, 6, 6},
                K7 = {7, 7, 7, 7}, K8 = {8, 8, 8, 8};
    const int rg = tid >> 2;  // 0..51
    const int g = tid & 3;
    const int ybase = rg * 5;
    const int jb = g * 8;
    const int ab = (ybase + 3) * 40 + jb;
    const u16x4 w0 = LDQ(ab), w1 = LDQ(ab + 40), w2 = LDQ(ab + 80),
                w3 = LDQ(ab + 120), w4 = LDQ(ab + 160), w5 = LDQ(ab + 200),
                w6 = LDQ(ab + 240), w7 = LDQ(ab + 280), w8 = LDQ(ab + 320),
                w9 = LDQ(ab + 360), w10 = LDQ(ab + 400), w11 = LDQ(ab + 440),
                w12 = LDQ(ab + 480), w13 = LDQ(ab + 520), w14 = LDQ(ab + 560),
                w15 = LDQ(ab + 600), w16 = LDQ(ab + 640), w17 = LDQ(ab + 680),
                w18 = LDQ(ab + 720), w19 = LDQ(ab + 760), w20 = LDQ(ab + 800);
    PFX(o0, w0, w1, w2, w3, w4, w5, w6, w7, w8, w9, w10, w11, w12, w13, w14, w15, w16);
    PFX(o1, w1, w2, w3, w4, w5, w6, w7, w8, w9, w10, w11, w12, w13, w14, w15, w16, w17);
    PFX(o2, w2, w3, w4, w5, w6, w7, w8, w9, w10, w11, w12, w13, w14, w15, w16, w17, w18);
    PFX(o3, w3, w4, w5, w6, w7, w8, w9, w10, w11, w12, w13, w14, w15, w16, w17, w18, w19);
    PFX(o4, w4, w5, w6, w7, w8, w9, w10, w11, w12, w13, w14, w15, w16, w17, w18, w19, w20);
    u16x4 mx = EMAX(EMAX(o0, o1), EMAX(EMAX(o2, o3), o4));
    int bm = BMOF(mx);
    int kc = 9;
    while (kc < bm) {
      const unsigned short q0 = (unsigned short)kc, q1 = (unsigned short)(kc + 1),
                           q2 = (unsigned short)(kc + 2), q3 = (unsigned short)(kc + 3);
      const u16x4 Kc0 = {q0, q0, q0, q0}, Kc1 = {q1, q1, q1, q1},
                  Kc2 = {q2, q2, q2, q2}, Kc3 = {q3, q3, q3, q3};
      const int lo2 = jb, hi2 = 278 * 40 + jb;
      const int aup = (ybase - kc + 8) * 40 + jb;
      const int adn = (ybase + kc + 11) * 40 + jb;
      const u16x4 t0 = LDQ(max(aup, lo2)), t1 = LDQ(max(aup + 40, lo2)),
                  t2 = LDQ(max(aup + 80, lo2)), t3 = LDQ(max(aup + 120, lo2)),
                  t4 = LDQ(max(aup + 160, lo2)), t5 = LDQ(max(aup + 200, lo2)),
                  t6 = LDQ(max(aup + 240, lo2)), t7 = LDQ(max(aup + 280, lo2));
      const u16x4 u0 = LDQ(min(adn, hi2)), u1 = LDQ(min(adn + 40, hi2)),
                  u2 = LDQ(min(adn + 80, hi2)), u3 = LDQ(min(adn + 120, hi2)),
                  u4 = LDQ(min(adn + 160, hi2)), u5 = LDQ(min(adn + 200, hi2)),
                  u6 = LDQ(min(adn + 240, hi2)), u7 = LDQ(min(adn + 280, hi2));
      TUP(o0, t3, t2, t1, t0, u0, u1, u2, u3);
      TUP(o1, t4, t3, t2, t1, u1, u2, u3, u4);
      TUP(o2, t5, t4, t3, t2, u2, u3, u4, u5);
      TUP(o3, t6, t5, t4, t3, u3, u4, u5, u6);
      TUP(o4, t7, t6, t5, t4, u4, u5, u6, u7);
      kc += 4;
      mx = EMAX(EMAX(o0, o1), EMAX(EMAX(o2, o3), o4));
      bm = BMOF(mx);
    }
    const size_t Db = (size_t)ch * 65536 + (size_t)ybase * 256 + x0 + g * 4;
#define STROW(j_, OJ)                                                           \
    if (ybase + (j_) <= 255) {                                                  \
      const unsigned long long ob = __builtin_bit_cast(unsigned long long, OJ); \
      *reinterpret_cast<unsigned int*>(&Dg[Db + (size_t)(j_) * 256]) =          \
          __builtin_amdgcn_perm((unsigned int)(ob >> 32), (unsigned int)ob,     \
                                0x06040200u);                                   \
    }
    STROW(0, o0) STROW(1, o1) STROW(2, o2) STROW(3, o3) STROW(4, o4)
#undef STROW
  }
}

// ---- epilogue tap-row macros ----
#define TAPROW(s_, t_, A0, A1, A2, A3, A4, A5, A6)                              \
  do {                                                                          \
    const unsigned int r0_ = R[(s_) + (t_)][0];                                 \
    const unsigned int r1_ = R[(s_) + (t_)][1];                                 \
    const unsigned int r2_ = R[(s_) + (t_)][2];                                 \
    A0 += (((__builtin_amdgcn_alignbyte(r1_, r0_, 1) + Cp) & 0x80808080u) >> 7);\
    A1 += (((__builtin_amdgcn_alignbyte(r1_, r0_, 2) + Cp) & 0x80808080u) >> 7);\
    A2 += (((__builtin_amdgcn_alignbyte(r1_, r0_, 3) + Cp) & 0x80808080u) >> 7);\
    A3 += (((r1_ + Cp) & 0x80808080u) >> 7);                                    \
    A4 += (((__builtin_amdgcn_alignbyte(r2_, r1_, 1) + Cp) & 0x80808080u) >> 7);\
    A5 += (((__builtin_amdgcn_alignbyte(r2_, r1_, 2) + Cp) & 0x80808080u) >> 7);\
    A6 += (((__builtin_amdgcn_alignbyte(r2_, r1_, 3) + Cp) & 0x80808080u) >> 7);\
  } while (0)

#define TAPROWC(s_, t_, A0, A1, A2, A4, A5, A6)                                 \
  do {                                                                          \
    const unsigned int r0_ = R[(s_) + (t_)][0];                                 \
    const unsigned int r1_ = R[(s_) + (t_)][1];                                 \
    const unsigned int r2_ = R[(s_) + (t_)][2];                                 \
    A0 += (((__builtin_amdgcn_alignbyte(r1_, r0_, 1) + Cp) & 0x80808080u) >> 7);\
    A1 += (((__builtin_amdgcn_alignbyte(r1_, r0_, 2) + Cp) & 0x80808080u) >> 7);\
    A2 += (((__builtin_amdgcn_alignbyte(r1_, r0_, 3) + Cp) & 0x80808080u) >> 7);\
    A4 += (((__builtin_amdgcn_alignbyte(r2_, r1_, 1) + Cp) & 0x80808080u) >> 7);\
    A5 += (((__builtin_amdgcn_alignbyte(r2_, r1_, 2) + Cp) & 0x80808080u) >> 7);\
    A6 += (((__builtin_amdgcn_alignbyte(r2_, r1_, 3) + Cp) & 0x80808080u) >> 7);\
  } while (0)

#define EPI(s_)                                                                 \
  do {                                                                          \
    const unsigned int Dc = R[(s_) + 3][1];                                     \
    const int d0_ = (int)(Dc & 255u);                                           \
    const int d1_ = (int)((Dc >> 8) & 255u);                                    \
    const int d2_ = (int)((Dc >> 16) & 255u);                                   \
    const int d3_ = (int)(Dc >> 24);                                            \
    const int i0_ = (max(d0_ - 1, 0) * 86) >> 8;                                \
    const int i1_ = (max(d1_ - 1, 0) * 86) >> 8;                                \
    const int i2_ = (max(d2_ - 1, 0) * 86) >> 8;                                \
    const int i3_ = (max(d3_ - 1, 0) * 86) >> 8;                                \
    const unsigned int Cp = (unsigned int)(127 - 3 * i0_) |                     \
                            ((unsigned int)(127 - 3 * i1_) << 8) |              \
                            ((unsigned int)(127 - 3 * i2_) << 16) |             \
                            ((unsigned int)(127 - 3 * i3_) << 24);              \
    unsigned int aA = 0, aB = 0, aC = 0, aD = 0;                                \
    TAPROW(s_, 0, aD, aD, aC, aC, aC, aD, aD);                                  \
    TAPROW(s_, 1, aD, aC, aB, aB, aB, aC, aD);                                  \
    TAPROW(s_, 2, aC, aB, aA, aA, aA, aB, aC);                                  \
    TAPROWC(s_, 3, aC, aB, aA, aA, aB, aC);                                     \
    TAPROW(s_, 4, aC, aB, aA, aA, aA, aB, aC);                                  \
    TAPROW(s_, 5, aD, aC, aB, aB, aB, aC, aD);                                  \
    TAPROW(s_, 6, aD, aD, aC, aC, aC, aD, aD);                                  \
    const float s0_ = fmaf((float)(aA & 255u), wA,                              \
                     fmaf((float)(aB & 255u), wB,                               \
                     fmaf((float)(aC & 255u), wC, (float)(aD & 255u) * wD)));   \
    const float s1f_ = fmaf((float)((aA >> 8) & 255u), wA,                      \
                      fmaf((float)((aB >> 8) & 255u), wB,                       \
                      fmaf((float)((aC >> 8) & 255u), wC,                       \
                           (float)((aD >> 8) & 255u) * wD)));                   \
    const float s2_ = fmaf((float)((aA >> 16) & 255u), wA,                      \
                     fmaf((float)((aB >> 16) & 255u), wB,                       \
                     fmaf((float)((aC >> 16) & 255u), wC,                       \
                          (float)((aD >> 16) & 255u) * wD)));                   \
    const float s3_ = fmaf((float)(aA >> 24), wA,                               \
                     fmaf((float)(aB >> 24), wB,                                \
                     fmaf((float)(aC >> 24), wC, (float)(aD >> 24) * wD)));     \
    const float cv0_ = W4 - s0_, cv1_ = W4 - s1f_;                              \
    const float cv2_ = W4 - s2_, cv3_ = W4 - s3_;                               \
    const float e0_ = fmaf(3.5f, (float)i0_, -0.35f * __logf(fmaxf(cv0_, 1e-30f))); \
    const float e1_ = fmaf(3.5f, (float)i1_, -0.35f * __logf(fmaxf(cv1_, 1e-30f))); \
    const float e2_ = fmaf(3.5f, (float)i2_, -0.35f * __logf(fmaxf(cv2_, 1e-30f))); \
    const float e3_ = fmaf(3.5f, (float)i3_, -0.35f * __logf(fmaxf(cv3_, 1e-30f))); \
    const float4 o4_ = make_float4(                                             \
        (d0_ > 0 && cv0_ > 1e-6f) ? e0_ : 0.0f,                                 \
        (d1_ > 0 && cv1_ > 1e-6f) ? e1_ : 0.0f,                                 \
        (d2_ > 0 && cv2_ > 1e-6f) ? e2_ : 0.0f,                                 \
        (d3_ > 0 && cv3_ > 1e-6f) ? e3_ : 0.0f);                                \
    *reinterpret_cast<float4*>(&out[obase + (size_t)(s_) * 256]) = o4_;         \
  } while (0)

// ---------- Kernel C: SWAR epilogue from staged D tile, 32x128 tiles ----------
__global__ __launch_bounds__(256) void k_final(const unsigned char* __restrict__ Dg,
                                               float* __restrict__ out) {
  const int ch = blockIdx.z;
  const int yt = blockIdx.y;  // 0..1
  const int xt = blockIdx.x;  // 0..7
  const int x0 = xt * 32;
  const int y0 = yt * 128;
  const int tid = threadIdx.x;

  __shared__ __align__(16) unsigned char Ds[134 * 44];

  const unsigned char* Dc0 = Dg + (size_t)ch * 65536;
#pragma unroll
  for (int it = 0; it < 6; ++it) {
    const int idx = it * 256 + tid;
    if (idx < 1340) {
      const int r = (idx * 6554) >> 16;  // /10
      const int c = idx - r * 10;
      const int y = y0 - 3 + r;
      const int xc = x0 - 4 + c * 4;
      unsigned int v = 0x7F7F7F7Fu;
      if ((unsigned int)y < 256u && (unsigned int)xc < 256u)
        v = *reinterpret_cast<const unsigned int*>(&Dc0[(size_t)y * 256 + xc]);
      *reinterpret_cast<unsigned int*>(&Ds[r * 44 + c * 4]) = v;
    }
  }
  __syncthreads();

  const float wA = 3.17814e-2f, wB = 2.35426e-3f, wC = 1.91126e-4f, wD = 1.35150e-5f;
  const float W4 = 8.0f * wA + 12.0f * wB + 16.0f * wC + 12.0f * wD;

  const int cg = tid & 7;
  const int rg = tid >> 3;
  const int rl0 = rg * 4;
  const int jb2 = cg * 4;
  const size_t obase = (size_t)ch * 65536 + (size_t)(y0 + rl0) * 256 + x0 + cg * 4;

  unsigned int R[10][3];
#pragma unroll
  for (int u = 0; u < 10; ++u) {
    const unsigned char* p = &Ds[(rl0 + u) * 44 + jb2];
    R[u][0] = *reinterpret_cast<const unsigned int*>(p);
    R[u][1] = *reinterpret_cast<const unsigned int*>(p + 4);
    R[u][2] = *reinterpret_cast<const unsigned int*>(p + 8);
  }

  EPI(0); EPI(1); EPI(2); EPI(3);
}

extern "C" void kernel_launch(void* const* d_in, const int* in_sizes, int n_in,
                              void* d_out, int out_size, void* d_ws, size_t ws_size,
                              hipStream_t stream) {
  const float* img = (const float*)d_in[0];
  float* out = (float*)d_out;
  unsigned char* Dbuf = (unsigned char*)d_ws;

  const int total = in_sizes[0];  // B*C*H*W
  const int nch = total >> 16;    // B*C (H=W=256)
  unsigned char* Dmat = Dbuf + (size_t)nch * CHB;  // u8 D, nch*65536

  k_rowdist<<<dim3(nch * 64), dim3(256), 0, stream>>>(img, Dbuf);
  k_coldist<<<dim3(16, nch), dim3(256), 0, stream>>>(Dbuf, Dmat);
  // k_final x5: idempotent (pure function Dmat -> out). Extra 4 launches are
  // the measurement: t_final ~ (dur_us - 55)/4.
  for (int rep = 0; rep < 5; ++rep)
    k_final<<<dim3(8, 2, nch), dim3(256), 0, stream>>>(Dmat, out);
}

// Round 15
// 43.641 us; speedup vs baseline: 3.0109x; 3.0109x over previous
//
#include <hip/hip_runtime.h>

// ConvDistanceTransform closed form:
//   D = Chebyshev distance transform of seeds (exact, separable)
//   i = (D-1)/3 ; out = 3.5*i - 0.35*log( sum_{q in 7x7, D(q)<=3i} exp(-|p-q|_2/0.35) )
// R15 = R11 kernels + T1 XCD-aware bijective block swizzle with a CONSISTENT
// channel->XCD chunk mapping across both kernels (d1 stays in XCD-local L2).

typedef unsigned short u16x4 __attribute__((ext_vector_type(4)));

#define BIGV (1 << 20)
#define ROWB 272  // u8 d1 row: 8 guard + 256 + 8 guard
#define CHB (256 * ROWB)

// ---------- Kernel A: per-row 1-D distance, wave-per-row register scans ----------
__global__ __launch_bounds__(256) void k_rowdist(const float* __restrict__ img,
                                                 unsigned char* __restrict__ d1) {
  const int lane = threadIdx.x & 63;
  const int wv = threadIdx.x >> 6;
  // XCD swizzle: hardware round-robins XCD by blockIdx%8; remap so XCD x gets
  // a contiguous logical chunk (channels [12x,12x+12) at nch=96).
  const int nwg = (int)gridDim.x;
  const int o = (int)blockIdx.x;
  const int l = (o & 7) * (nwg >> 3) + (o >> 3);
  const int row = l * 4 + wv;  // ch*256 + y
  const int x0 = lane * 4;

  const float4 v = *reinterpret_cast<const float4*>(&img[(size_t)row * 256 + x0]);

  int c0 = (v.x != 0.0f) ? -x0 : BIGV;
  int c1 = (v.y != 0.0f) ? -(x0 + 1) : BIGV;
  int c2 = (v.z != 0.0f) ? -(x0 + 2) : BIGV;
  int c3 = (v.w != 0.0f) ? -(x0 + 3) : BIGV;
  const int p0 = c0;
  const int p1 = min(c1, p0);
  const int p2 = min(c2, p1);
  const int p3 = min(c3, p2);
  int incl = p3;
#pragma unroll
  for (int off = 1; off < 64; off <<= 1) {
    int o2 = __shfl_up(incl, off, 64);
    if (lane >= off) incl = min(incl, o2);
  }
  int excl = __shfl_up(incl, 1, 64);
  if (lane == 0) excl = BIGV;
  const int df0 = x0 + min(p0, excl);
  const int df1 = x0 + 1 + min(p1, excl);
  const int df2 = x0 + 2 + min(p2, excl);
  const int df3 = x0 + 3 + min(p3, excl);

  int g0 = (v.x != 0.0f) ? x0 : BIGV;
  int g1 = (v.y != 0.0f) ? (x0 + 1) : BIGV;
  int g2 = (v.z != 0.0f) ? (x0 + 2) : BIGV;
  int g3 = (v.w != 0.0f) ? (x0 + 3) : BIGV;
  const int q3 = g3;
  const int q2 = min(g2, q3);
  const int q1 = min(g1, q2);
  const int q0 = min(g0, q1);
  int incl2 = q0;
#pragma unroll
  for (int off = 1; off < 64; off <<= 1) {
    int o2 = __shfl_down(incl2, off, 64);
    if (lane < 64 - off) incl2 = min(incl2, o2);
  }
  int excl2 = __shfl_down(incl2, 1, 64);
  if (lane == 63) excl2 = BIGV;
  const int db0 = min(q0, excl2) - x0;
  const int db1 = min(q1, excl2) - (x0 + 1);
  const int db2 = min(q2, excl2) - (x0 + 2);
  const int db3 = min(q3, excl2) - (x0 + 3);

  const unsigned int d0 = (unsigned int)min(min(df0, db0), 127);
  const unsigned int d1v = (unsigned int)min(min(df1, db1), 127);
  const unsigned int d2 = (unsigned int)min(min(df2, db2), 127);
  const unsigned int d3 = (unsigned int)min(min(df3, db3), 127);
  const int ch = row >> 8, y = row & 255;
  const size_t base = (size_t)ch * CHB + (size_t)y * ROWB;
  *reinterpret_cast<unsigned int*>(&d1[base + 8 + x0]) =
      d0 | (d1v << 8) | (d2 << 16) | (d3 << 24);
  // guards = 0: staged ghost cols exit the colpass immediately (Ds fixup -> 127)
  if (lane < 2)
    *reinterpret_cast<unsigned int*>(&d1[base + lane * 4]) = 0u;
  else if (lane >= 62)
    *reinterpret_cast<unsigned int*>(&d1[base + 264 + (lane - 62) * 4]) = 0u;
}

// ---- epilogue tap-row macros: accumulators passed BY NAME (never an array) ----
#define TAPROW(s_, t_, A0, A1, A2, A3, A4, A5, A6)                              \
  do {                                                                          \
    const unsigned int r0_ = R[(s_) + (t_)][0];                                 \
    const unsigned int r1_ = R[(s_) + (t_)][1];                                 \
    const unsigned int r2_ = R[(s_) + (t_)][2];                                 \
    A0 += (((__builtin_amdgcn_alignbyte(r1_, r0_, 1) + Cp) & 0x80808080u) >> 7);\
    A1 += (((__builtin_amdgcn_alignbyte(r1_, r0_, 2) + Cp) & 0x80808080u) >> 7);\
    A2 += (((__builtin_amdgcn_alignbyte(r1_, r0_, 3) + Cp) & 0x80808080u) >> 7);\
    A3 += (((r1_ + Cp) & 0x80808080u) >> 7);                                    \
    A4 += (((__builtin_amdgcn_alignbyte(r2_, r1_, 1) + Cp) & 0x80808080u) >> 7);\
    A5 += (((__builtin_amdgcn_alignbyte(r2_, r1_, 2) + Cp) & 0x80808080u) >> 7);\
    A6 += (((__builtin_amdgcn_alignbyte(r2_, r1_, 3) + Cp) & 0x80808080u) >> 7);\
  } while (0)

#define TAPROWC(s_, t_, A0, A1, A2, A4, A5, A6) /* center row: dx=0 skipped */  \
  do {                                                                          \
    const unsigned int r0_ = R[(s_) + (t_)][0];                                 \
    const unsigned int r1_ = R[(s_) + (t_)][1];                                 \
    const unsigned int r2_ = R[(s_) + (t_)][2];                                 \
    A0 += (((__builtin_amdgcn_alignbyte(r1_, r0_, 1) + Cp) & 0x80808080u) >> 7);\
    A1 += (((__builtin_amdgcn_alignbyte(r1_, r0_, 2) + Cp) & 0x80808080u) >> 7);\
    A2 += (((__builtin_amdgcn_alignbyte(r1_, r0_, 3) + Cp) & 0x80808080u) >> 7);\
    A4 += (((__builtin_amdgcn_alignbyte(r2_, r1_, 1) + Cp) & 0x80808080u) >> 7);\
    A5 += (((__builtin_amdgcn_alignbyte(r2_, r1_, 2) + Cp) & 0x80808080u) >> 7);\
    A6 += (((__builtin_amdgcn_alignbyte(r2_, r1_, 3) + Cp) & 0x80808080u) >> 7);\
  } while (0)

// Fully scalar epilogue step: no unions, no address-taken locals.
#define EPI(s_)                                                                 \
  do {                                                                          \
    const unsigned int Dc = R[(s_) + 3][1];                                     \
    const int d0_ = (int)(Dc & 255u);                                           \
    const int d1_ = (int)((Dc >> 8) & 255u);                                    \
    const int d2_ = (int)((Dc >> 16) & 255u);                                   \
    const int d3_ = (int)(Dc >> 24);                                            \
    const int i0_ = (max(d0_ - 1, 0) * 86) >> 8; /* exact floor((d-1)/3) */     \
    const int i1_ = (max(d1_ - 1, 0) * 86) >> 8;                                \
    const int i2_ = (max(d2_ - 1, 0) * 86) >> 8;                                \
    const int i3_ = (max(d3_ - 1, 0) * 86) >> 8;                                \
    const unsigned int Cp = (unsigned int)(127 - 3 * i0_) |                     \
                            ((unsigned int)(127 - 3 * i1_) << 8) |              \
                            ((unsigned int)(127 - 3 * i2_) << 16) |             \
                            ((unsigned int)(127 - 3 * i3_) << 24);              \
    unsigned int aA = 0, aB = 0, aC = 0, aD = 0;                                \
    TAPROW(s_, 0, aD, aD, aC, aC, aC, aD, aD);                                  \
    TAPROW(s_, 1, aD, aC, aB, aB, aB, aC, aD);                                  \
    TAPROW(s_, 2, aC, aB, aA, aA, aA, aB, aC);                                  \
    TAPROWC(s_, 3, aC, aB, aA, aA, aB, aC);                                     \
    TAPROW(s_, 4, aC, aB, aA, aA, aA, aB, aC);                                  \
    TAPROW(s_, 5, aD, aC, aB, aB, aB, aC, aD);                                  \
    TAPROW(s_, 6, aD, aD, aC, aC, aC, aD, aD);                                  \
    const float s0_ = fmaf((float)(aA & 255u), wA,                              \
                     fmaf((float)(aB & 255u), wB,                               \
                     fmaf((float)(aC & 255u), wC, (float)(aD & 255u) * wD)));   \
    const float s1_ = fmaf((float)((aA >> 8) & 255u), wA,                       \
                     fmaf((float)((aB >> 8) & 255u), wB,                        \
                     fmaf((float)((aC >> 8) & 255u), wC,                        \
                          (float)((aD >> 8) & 255u) * wD)));                    \
    const float s2_ = fmaf((float)((aA >> 16) & 255u), wA,                      \
                     fmaf((float)((aB >> 16) & 255u), wB,                       \
                     fmaf((float)((aC >> 16) & 255u), wC,                       \
                          (float)((aD >> 16) & 255u) * wD)));                   \
    const float s3_ = fmaf((float)(aA >> 24), wA,                               \
                     fmaf((float)(aB >> 24), wB,                                \
                     fmaf((float)(aC >> 24), wC, (float)(aD >> 24) * wD)));     \
    const float cv0_ = W4 - s0_, cv1_ = W4 - s1_;                               \
    const float cv2_ = W4 - s2_, cv3_ = W4 - s3_;                               \
    const float e0_ = fmaf(3.5f, (float)i0_, -0.35f * __logf(fmaxf(cv0_, 1e-30f))); \
    const float e1_ = fmaf(3.5f, (float)i1_, -0.35f * __logf(fmaxf(cv1_, 1e-30f))); \
    const float e2_ = fmaf(3.5f, (float)i2_, -0.35f * __logf(fmaxf(cv2_, 1e-30f))); \
    const float e3_ = fmaf(3.5f, (float)i3_, -0.35f * __logf(fmaxf(cv3_, 1e-30f))); \
    const float4 o4_ = make_float4(                                             \
        (d0_ > 0 && cv0_ > 1e-6f) ? e0_ : 0.0f,                                 \
        (d1_ > 0 && cv1_ > 1e-6f) ? e1_ : 0.0f,                                 \
        (d2_ > 0 && cv2_ > 1e-6f) ? e2_ : 0.0f,                                 \
        (d3_ > 0 && cv3_ > 1e-6f) ? e3_ : 0.0f);                                \
    *reinterpret_cast<float4*>(&out[obase + (size_t)(s_) * 256]) = o4_;         \
  } while (0)

#define LDQ(off) (*reinterpret_cast<const u16x4*>(&s1[(off)]))
#define EMIN __builtin_elementwise_min
#define EMAX __builtin_elementwise_max

// ---------- Kernel B: column transform + SWAR epilogue, 32-col x 128-row tiles ----
__global__ __launch_bounds__(256) void k_fused(const unsigned char* __restrict__ d1,
                                               float* __restrict__ out) {
  // XCD swizzle consistent with k_rowdist: XCD x gets channels [12x,12x+12).
  const int nwg = (int)gridDim.x;  // nch*16
  const int o = (int)blockIdx.x;
  const int l = (o & 7) * (nwg >> 3) + (o >> 3);
  const int xt = l & 7;         // 0..7
  const int yt = (l >> 3) & 1;  // 0..1
  const int ch = l >> 4;
  const int x0 = xt * 32;
  const int y0 = yt * 128;
  const int tid = threadIdx.x;
  const int lastxt = 7;

  __shared__ __align__(16) unsigned char s1[256 * 96];  // u16; col j <-> img x0-8+j
  __shared__ __align__(16) unsigned char Ds[134 * 44];  // u8; row r <-> y = y0+r-3

  // ---- stage u8 d1 (48 cols, all 256 rows), expand to u16 via perm ----
  const unsigned char* src = d1 + (size_t)ch * CHB + x0;
#pragma unroll
  for (int it = 0; it < 3; ++it) {
    const int idx = it * 256 + tid;     // 0..767
    const int y = (idx * 21846) >> 16;  // /3
    const int seg = idx - y * 3;
    const uint4 q = *reinterpret_cast<const uint4*>(&src[y * ROWB + seg * 16]);
    uint4 lo, hi;
    lo.x = __builtin_amdgcn_perm(0u, q.x, 0x0C010C00u);
    lo.y = __builtin_amdgcn_perm(0u, q.x, 0x0C030C02u);
    lo.z = __builtin_amdgcn_perm(0u, q.y, 0x0C010C00u);
    lo.w = __builtin_amdgcn_perm(0u, q.y, 0x0C030C02u);
    hi.x = __builtin_amdgcn_perm(0u, q.z, 0x0C010C00u);
    hi.y = __builtin_amdgcn_perm(0u, q.z, 0x0C030C02u);
    hi.z = __builtin_amdgcn_perm(0u, q.w, 0x0C010C00u);
    hi.w = __builtin_amdgcn_perm(0u, q.w, 0x0C030C02u);
    *reinterpret_cast<uint4*>(&s1[y * 96 + seg * 32]) = lo;
    *reinterpret_cast<uint4*>(&s1[y * 96 + seg * 32 + 16]) = hi;
  }
  __syncthreads();

  // ---- column pass: tree-combined prefix k=1..8, then 4-chunk tail ----
  const u16x4 K1 = {1, 1, 1, 1}, K2 = {2, 2, 2, 2}, K3 = {3, 3, 3, 3},
              K4 = {4, 4, 4, 4}, K5 = {5, 5, 5, 5}, K6 = {6, 6, 6, 6},
              K7 = {7, 7, 7, 7}, K8 = {8, 8, 8, 8};
#pragma unroll 1
  for (int it = 0; it < 6; ++it) {
    const int idx = it * 256 + tid;  // 0..1535
    if (idx >= 1340) break;
    const int r = (idx * 6554) >> 16;  // /10
    const int g = idx - r * 10;        // 0..9 (cols x0-4+4g ..)
    const int y = y0 + r - 3;
    const bool ghost =
        (xt == 0 && g == 0) || (xt == lastxt && g == 9) || y < 0 || y > 255;
    if (ghost) {  // outside image: always-excluded
      *reinterpret_cast<unsigned int*>(&Ds[r * 44 + g * 4]) = 0x7F7F7F7Fu;
      continue;
    }
    const int jb = 8 + 8 * g;
    const int rb = y * 96 + jb;
    const int bot = 255 * 96 + jb;
    const u16x4 b0 = LDQ(rb);
    const u16x4 u1 = LDQ(max(rb - 96, jb));
    const u16x4 u2 = LDQ(max(rb - 192, jb));
    const u16x4 u3 = LDQ(max(rb - 288, jb));
    const u16x4 u4 = LDQ(max(rb - 384, jb));
    const u16x4 u5 = LDQ(max(rb - 480, jb));
    const u16x4 u6 = LDQ(max(rb - 576, jb));
    const u16x4 u7 = LDQ(max(rb - 672, jb));
    const u16x4 u8 = LDQ(max(rb - 768, jb));
    const u16x4 w1 = LDQ(min(rb + 96, bot));
    const u16x4 w2 = LDQ(min(rb + 192, bot));
    const u16x4 w3 = LDQ(min(rb + 288, bot));
    const u16x4 w4 = LDQ(min(rb + 384, bot));
    const u16x4 w5 = LDQ(min(rb + 480, bot));
    const u16x4 w6 = LDQ(min(rb + 576, bot));
    const u16x4 w7 = LDQ(min(rb + 672, bot));
    const u16x4 w8 = LDQ(min(rb + 768, bot));
    const u16x4 mu = EMIN(EMIN(EMIN(EMAX(u1, K1), EMAX(u2, K2)),
                                EMIN(EMAX(u3, K3), EMAX(u4, K4))),
                          EMIN(EMIN(EMAX(u5, K5), EMAX(u6, K6)),
                                EMIN(EMAX(u7, K7), EMAX(u8, K8))));
    const u16x4 mw = EMIN(EMIN(EMIN(EMAX(w1, K1), EMAX(w2, K2)),
                                EMIN(EMAX(w3, K3), EMAX(w4, K4))),
                          EMIN(EMIN(EMAX(w5, K5), EMAX(w6, K6)),
                                EMIN(EMAX(w7, K7), EMAX(w8, K8))));
    u16x4 b = EMIN(b0, EMIN(mu, mw));
    unsigned long long bb = __builtin_bit_cast(unsigned long long, b);
    unsigned int blo = (unsigned int)bb, bhi = (unsigned int)(bb >> 32);
    int bm = max(max((int)(blo & 0xFFFFu), (int)(blo >> 16)),
                 max((int)(bhi & 0xFFFFu), (int)(bhi >> 16)));
    int k = 9;
    int au = rb - 768, ad = rb + 768;
    while (k < bm) {  // over-iterations are provable no-ops
      const unsigned short t1 = (unsigned short)k, t2 = (unsigned short)(k + 1),
                           t3 = (unsigned short)(k + 2), t4 = (unsigned short)(k + 3);
      const u16x4 c1 = {t1, t1, t1, t1}, c2 = {t2, t2, t2, t2},
                  c3 = {t3, t3, t3, t3}, c4 = {t4, t4, t4, t4};
      const u16x4 a1 = LDQ(max(au - 96, jb));
      const u16x4 a2 = LDQ(max(au - 192, jb));
      const u16x4 a3 = LDQ(max(au - 288, jb));
      const u16x4 a4 = LDQ(max(au - 384, jb));
      const u16x4 e1 = LDQ(min(ad + 96, bot));
      const u16x4 e2 = LDQ(min(ad + 192, bot));
      const u16x4 e3 = LDQ(min(ad + 288, bot));
      const u16x4 e4 = LDQ(min(ad + 384, bot));
      const u16x4 t = EMIN(EMIN(EMIN(EMAX(a1, c1), EMAX(a2, c2)),
                                 EMIN(EMAX(a3, c3), EMAX(a4, c4))),
                           EMIN(EMIN(EMAX(e1, c1), EMAX(e2, c2)),
                                 EMIN(EMAX(e3, c3), EMAX(e4, c4))));
      b = EMIN(b, t);
      au -= 384;
      ad += 384;
      k += 4;
      bb = __builtin_bit_cast(unsigned long long, b);
      blo = (unsigned int)bb;
      bhi = (unsigned int)(bb >> 32);
      bm = max(max((int)(blo & 0xFFFFu), (int)(blo >> 16)),
               max((int)(bhi & 0xFFFFu), (int)(bhi >> 16)));
    }
    const unsigned int packed = __builtin_amdgcn_perm(bhi, blo, 0x06040200u);
    *reinterpret_cast<unsigned int*>(&Ds[r * 44 + g * 4]) = packed;
  }
  __syncthreads();

  // ---- SWAR epilogue: thread tile = 4 cols x 4 rows; fully macro-unrolled ----
  // 4 merged weight classes (|out err| <= 0.375, threshold 0.825):
  const float wA = 3.17814e-2f, wB = 2.35426e-3f, wC = 1.91126e-4f, wD = 1.35150e-5f;
  const float W4 = 8.0f * wA + 12.0f * wB + 16.0f * wC + 12.0f * wD;

  const int cg = tid & 7;   // col group: center cols x0+4cg .. +3
  const int rg = tid >> 3;  // 0..31 (4 rows each)
  const int rl0 = rg * 4;
  const int jb2 = cg * 4;
  const size_t obase = (size_t)ch * 65536 + (size_t)(y0 + rl0) * 256 + x0 + cg * 4;

  unsigned int R[10][3];
#pragma unroll
  for (int u = 0; u < 10; ++u) {
    const unsigned char* p = &Ds[(rl0 + u) * 44 + jb2];
    R[u][0] = *reinterpret_cast<const unsigned int*>(p);
    R[u][1] = *reinterpret_cast<const unsigned int*>(p + 4);
    R[u][2] = *reinterpret_cast<const unsigned int*>(p + 8);
  }

  EPI(0); EPI(1); EPI(2); EPI(3);
}

extern "C" void kernel_launch(void* const* d_in, const int* in_sizes, int n_in,
                              void* d_out, int out_size, void* d_ws, size_t ws_size,
                              hipStream_t stream) {
  const float* img = (const float*)d_in[0];
  float* out = (float*)d_out;
  unsigned char* Dbuf = (unsigned char*)d_ws;

  const int total = in_sizes[0];  // B*C*H*W
  const int nch = total >> 16;    // B*C (H=W=256)

  k_rowdist<<<dim3(nch * 64), dim3(256), 0, stream>>>(img, Dbuf);
  k_fused<<<dim3(nch * 16), dim3(256), 0, stream>>>(Dbuf, out);
}

// Round 16
// 43.431 us; speedup vs baseline: 3.0255x; 1.0048x over previous
//
#include <hip/hip_runtime.h>

// ConvDistanceTransform closed form:
//   D = Chebyshev distance transform of seeds (exact, separable)
//   i = (D-1)/3 ; out = 3.5*i - 0.35*log( sum_{q in 7x7, D(q)<=3i} exp(-|p-q|_2/0.35) )
// R16 = R15 (XCD swizzle) + row-major shared-align epilogue: each of the 10
// window rows is loaded and byte-shifted ONCE, feeding all 4 output rows'
// class accumulators (named scalars). Integer math identical to R15.

typedef unsigned short u16x4 __attribute__((ext_vector_type(4)));

#define BIGV (1 << 20)
#define ROWB 272  // u8 d1 row: 8 guard + 256 + 8 guard
#define CHB (256 * ROWB)

// ---------- Kernel A: per-row 1-D distance, wave-per-row register scans ----------
__global__ __launch_bounds__(256) void k_rowdist(const float* __restrict__ img,
                                                 unsigned char* __restrict__ d1) {
  const int lane = threadIdx.x & 63;
  const int wv = threadIdx.x >> 6;
  const int nwg = (int)gridDim.x;
  const int o = (int)blockIdx.x;
  const int l = (o & 7) * (nwg >> 3) + (o >> 3);  // XCD-chunk swizzle
  const int row = l * 4 + wv;  // ch*256 + y
  const int x0 = lane * 4;

  const float4 v = *reinterpret_cast<const float4*>(&img[(size_t)row * 256 + x0]);

  int c0 = (v.x != 0.0f) ? -x0 : BIGV;
  int c1 = (v.y != 0.0f) ? -(x0 + 1) : BIGV;
  int c2 = (v.z != 0.0f) ? -(x0 + 2) : BIGV;
  int c3 = (v.w != 0.0f) ? -(x0 + 3) : BIGV;
  const int p0 = c0;
  const int p1 = min(c1, p0);
  const int p2 = min(c2, p1);
  const int p3 = min(c3, p2);
  int incl = p3;
#pragma unroll
  for (int off = 1; off < 64; off <<= 1) {
    int o2 = __shfl_up(incl, off, 64);
    if (lane >= off) incl = min(incl, o2);
  }
  int excl = __shfl_up(incl, 1, 64);
  if (lane == 0) excl = BIGV;
  const int df0 = x0 + min(p0, excl);
  const int df1 = x0 + 1 + min(p1, excl);
  const int df2 = x0 + 2 + min(p2, excl);
  const int df3 = x0 + 3 + min(p3, excl);

  int g0 = (v.x != 0.0f) ? x0 : BIGV;
  int g1 = (v.y != 0.0f) ? (x0 + 1) : BIGV;
  int g2 = (v.z != 0.0f) ? (x0 + 2) : BIGV;
  int g3 = (v.w != 0.0f) ? (x0 + 3) : BIGV;
  const int q3 = g3;
  const int q2 = min(g2, q3);
  const int q1 = min(g1, q2);
  const int q0 = min(g0, q1);
  int incl2 = q0;
#pragma unroll
  for (int off = 1; off < 64; off <<= 1) {
    int o2 = __shfl_down(incl2, off, 64);
    if (lane < 64 - off) incl2 = min(incl2, o2);
  }
  int excl2 = __shfl_down(incl2, 1, 64);
  if (lane == 63) excl2 = BIGV;
  const int db0 = min(q0, excl2) - x0;
  const int db1 = min(q1, excl2) - (x0 + 1);
  const int db2 = min(q2, excl2) - (x0 + 2);
  const int db3 = min(q3, excl2) - (x0 + 3);

  const unsigned int d0 = (unsigned int)min(min(df0, db0), 127);
  const unsigned int d1v = (unsigned int)min(min(df1, db1), 127);
  const unsigned int d2 = (unsigned int)min(min(df2, db2), 127);
  const unsigned int d3 = (unsigned int)min(min(df3, db3), 127);
  const int ch = row >> 8, y = row & 255;
  const size_t base = (size_t)ch * CHB + (size_t)y * ROWB;
  *reinterpret_cast<unsigned int*>(&d1[base + 8 + x0]) =
      d0 | (d1v << 8) | (d2 << 16) | (d3 << 24);
  if (lane < 2)
    *reinterpret_cast<unsigned int*>(&d1[base + lane * 4]) = 0u;
  else if (lane >= 62)
    *reinterpret_cast<unsigned int*>(&d1[base + 264 + (lane - 62) * 4]) = 0u;
}

#define LDQ(off) (*reinterpret_cast<const u16x4*>(&s1[(off)]))
#define EMIN __builtin_elementwise_min
#define EMAX __builtin_elementwise_max

// ---- epilogue: row-major shared-align tap scatter ----
#define IND(q_, CP) ((((q_) + (CP)) & 0x80808080u) >> 7)

// pattern rows (t and 6-t identical): classes A..D merged by radius
#define PT0(s_)                                                                 \
  aD##s_ += IND(q0, Cp##s_); aD##s_ += IND(q1, Cp##s_);                         \
  aC##s_ += IND(q2, Cp##s_); aC##s_ += IND(q3, Cp##s_);                         \
  aC##s_ += IND(q4, Cp##s_); aD##s_ += IND(q5, Cp##s_);                         \
  aD##s_ += IND(q6, Cp##s_);
#define PT1(s_)                                                                 \
  aD##s_ += IND(q0, Cp##s_); aC##s_ += IND(q1, Cp##s_);                         \
  aB##s_ += IND(q2, Cp##s_); aB##s_ += IND(q3, Cp##s_);                         \
  aB##s_ += IND(q4, Cp##s_); aC##s_ += IND(q5, Cp##s_);                         \
  aD##s_ += IND(q6, Cp##s_);
#define PT2(s_)                                                                 \
  aC##s_ += IND(q0, Cp##s_); aB##s_ += IND(q1, Cp##s_);                         \
  aA##s_ += IND(q2, Cp##s_); aA##s_ += IND(q3, Cp##s_);                         \
  aA##s_ += IND(q4, Cp##s_); aB##s_ += IND(q5, Cp##s_);                         \
  aC##s_ += IND(q6, Cp##s_);
#define PT3(s_) /* center row: dx=0 skipped */                                  \
  aC##s_ += IND(q0, Cp##s_); aB##s_ += IND(q1, Cp##s_);                         \
  aA##s_ += IND(q2, Cp##s_);                                                    \
  aA##s_ += IND(q4, Cp##s_); aB##s_ += IND(q5, Cp##s_);                         \
  aC##s_ += IND(q6, Cp##s_);

#define ROWU(u_, ...)                                                           \
  do {                                                                          \
    const unsigned char* pu_ = &Ds[(rl0 + (u_)) * 44 + jb2];                    \
    const unsigned int R0_ = *reinterpret_cast<const unsigned int*>(pu_);       \
    const unsigned int R1_ = *reinterpret_cast<const unsigned int*>(pu_ + 4);   \
    const unsigned int R2_ = *reinterpret_cast<const unsigned int*>(pu_ + 8);   \
    const unsigned int q0 = __builtin_amdgcn_alignbyte(R1_, R0_, 1);            \
    const unsigned int q1 = __builtin_amdgcn_alignbyte(R1_, R0_, 2);            \
    const unsigned int q2 = __builtin_amdgcn_alignbyte(R1_, R0_, 3);            \
    const unsigned int q3 = R1_;                                                \
    const unsigned int q4 = __builtin_amdgcn_alignbyte(R2_, R1_, 1);            \
    const unsigned int q5 = __builtin_amdgcn_alignbyte(R2_, R1_, 2);            \
    const unsigned int q6 = __builtin_amdgcn_alignbyte(R2_, R1_, 3);            \
    (void)q0; (void)q1; (void)q2; (void)q3; (void)q4; (void)q5; (void)q6;       \
    __VA_ARGS__                                                                 \
  } while (0)

#define CPSET(s_, DC)                                                           \
  const unsigned int Cp##s_ =                                                   \
      (unsigned int)(127 - 3 * ((max((int)((DC)&255u) - 1, 0) * 86) >> 8)) |    \
      ((unsigned int)(127 - 3 * ((max((int)(((DC) >> 8) & 255u) - 1, 0) * 86) >> 8)) << 8) | \
      ((unsigned int)(127 - 3 * ((max((int)(((DC) >> 16) & 255u) - 1, 0) * 86) >> 8)) << 16) | \
      ((unsigned int)(127 - 3 * ((max((int)((DC) >> 24) - 1, 0) * 86) >> 8)) << 24)

#define FIN(s_, DC)                                                             \
  do {                                                                          \
    const int d0_ = (int)((DC)&255u);                                           \
    const int d1_ = (int)(((DC) >> 8) & 255u);                                  \
    const int d2_ = (int)(((DC) >> 16) & 255u);                                 \
    const int d3_ = (int)((DC) >> 24);                                          \
    const int i0_ = (max(d0_ - 1, 0) * 86) >> 8;                                \
    const int i1_ = (max(d1_ - 1, 0) * 86) >> 8;                                \
    const int i2_ = (max(d2_ - 1, 0) * 86) >> 8;                                \
    const int i3_ = (max(d3_ - 1, 0) * 86) >> 8;                                \
    const float s0_ = fmaf((float)(aA##s_ & 255u), wA,                          \
                     fmaf((float)(aB##s_ & 255u), wB,                           \
                     fmaf((float)(aC##s_ & 255u), wC,                           \
                          (float)(aD##s_ & 255u) * wD)));                       \
    const float s1_ = fmaf((float)((aA##s_ >> 8) & 255u), wA,                   \
                     fmaf((float)((aB##s_ >> 8) & 255u), wB,                    \
                     fmaf((float)((aC##s_ >> 8) & 255u), wC,                    \
                          (float)((aD##s_ >> 8) & 255u) * wD)));                \
    const float s2_ = fmaf((float)((aA##s_ >> 16) & 255u), wA,                  \
                     fmaf((float)((aB##s_ >> 16) & 255u), wB,                   \
                     fmaf((float)((aC##s_ >> 16) & 255u), wC,                   \
                          (float)((aD##s_ >> 16) & 255u) * wD)));               \
    const float s3_ = fmaf((float)(aA##s_ >> 24), wA,                           \
                     fmaf((float)(aB##s_ >> 24), wB,                            \
                     fmaf((float)(aC##s_ >> 24), wC,                            \
                          (float)(aD##s_ >> 24) * wD)));                        \
    const float cv0_ = W4 - s0_, cv1_ = W4 - s1_;                               \
    const float cv2_ = W4 - s2_, cv3_ = W4 - s3_;                               \
    const float e0_ = fmaf(3.5f, (float)i0_, -0.35f * __logf(fmaxf(cv0_, 1e-30f))); \
    const float e1_ = fmaf(3.5f, (float)i1_, -0.35f * __logf(fmaxf(cv1_, 1e-30f))); \
    const float e2_ = fmaf(3.5f, (float)i2_, -0.35f * __logf(fmaxf(cv2_, 1e-30f))); \
    const float e3_ = fmaf(3.5f, (float)i3_, -0.35f * __logf(fmaxf(cv3_, 1e-30f))); \
    const float4 o4_ = make_float4(                                             \
        (d0_ > 0 && cv0_ > 1e-6f) ? e0_ : 0.0f,                                 \
        (d1_ > 0 && cv1_ > 1e-6f) ? e1_ : 0.0f,                                 \
        (d2_ > 0 && cv2_ > 1e-6f) ? e2_ : 0.0f,                                 \
        (d3_ > 0 && cv3_ > 1e-6f) ? e3_ : 0.0f);                                \
    *reinterpret_cast<float4*>(&out[obase + (size_t)(s_) * 256]) = o4_;         \
  } while (0)

// ---------- Kernel B: column transform + SWAR epilogue, 32-col x 128-row tiles ----
__global__ __launch_bounds__(256) void k_fused(const unsigned char* __restrict__ d1,
                                               float* __restrict__ out) {
  const int nwg = (int)gridDim.x;  // nch*16
  const int o = (int)blockIdx.x;
  const int l = (o & 7) * (nwg >> 3) + (o >> 3);  // XCD-chunk swizzle
  const int xt = l & 7;
  const int yt = (l >> 3) & 1;
  const int ch = l >> 4;
  const int x0 = xt * 32;
  const int y0 = yt * 128;
  const int tid = threadIdx.x;
  const int lastxt = 7;

  __shared__ __align__(16) unsigned char s1[256 * 96];  // u16; col j <-> img x0-8+j
  __shared__ __align__(16) unsigned char Ds[134 * 44];  // u8; row r <-> y = y0+r-3

  // ---- stage u8 d1 (48 cols, all 256 rows), expand to u16 via perm ----
  const unsigned char* src = d1 + (size_t)ch * CHB + x0;
#pragma unroll
  for (int it = 0; it < 3; ++it) {
    const int idx = it * 256 + tid;     // 0..767
    const int y = (idx * 21846) >> 16;  // /3
    const int seg = idx - y * 3;
    const uint4 q = *reinterpret_cast<const uint4*>(&src[y * ROWB + seg * 16]);
    uint4 lo, hi;
    lo.x = __builtin_amdgcn_perm(0u, q.x, 0x0C010C00u);
    lo.y = __builtin_amdgcn_perm(0u, q.x, 0x0C030C02u);
    lo.z = __builtin_amdgcn_perm(0u, q.y, 0x0C010C00u);
    lo.w = __builtin_amdgcn_perm(0u, q.y, 0x0C030C02u);
    hi.x = __builtin_amdgcn_perm(0u, q.z, 0x0C010C00u);
    hi.y = __builtin_amdgcn_perm(0u, q.z, 0x0C030C02u);
    hi.z = __builtin_amdgcn_perm(0u, q.w, 0x0C010C00u);
    hi.w = __builtin_amdgcn_perm(0u, q.w, 0x0C030C02u);
    *reinterpret_cast<uint4*>(&s1[y * 96 + seg * 32]) = lo;
    *reinterpret_cast<uint4*>(&s1[y * 96 + seg * 32 + 16]) = hi;
  }
  __syncthreads();

  // ---- column pass (unchanged from R15) ----
  const u16x4 K1 = {1, 1, 1, 1}, K2 = {2, 2, 2, 2}, K3 = {3, 3, 3, 3},
              K4 = {4, 4, 4, 4}, K5 = {5, 5, 5, 5}, K6 = {6, 6, 6, 6},
              K7 = {7, 7, 7, 7}, K8 = {8, 8, 8, 8};
#pragma unroll 1
  for (int it = 0; it < 6; ++it) {
    const int idx = it * 256 + tid;  // 0..1535
    if (idx >= 1340) break;
    const int r = (idx * 6554) >> 16;  // /10
    const int g = idx - r * 10;
    const int y = y0 + r - 3;
    const bool ghost =
        (xt == 0 && g == 0) || (xt == lastxt && g == 9) || y < 0 || y > 255;
    if (ghost) {
      *reinterpret_cast<unsigned int*>(&Ds[r * 44 + g * 4]) = 0x7F7F7F7Fu;
      continue;
    }
    const int jb = 8 + 8 * g;
    const int rb = y * 96 + jb;
    const int bot = 255 * 96 + jb;
    const u16x4 b0 = LDQ(rb);
    const u16x4 u1 = LDQ(max(rb - 96, jb));
    const u16x4 u2 = LDQ(max(rb - 192, jb));
    const u16x4 u3 = LDQ(max(rb - 288, jb));
    const u16x4 u4 = LDQ(max(rb - 384, jb));
    const u16x4 u5 = LDQ(max(rb - 480, jb));
    const u16x4 u6 = LDQ(max(rb - 576, jb));
    const u16x4 u7 = LDQ(max(rb - 672, jb));
    const u16x4 u8 = LDQ(max(rb - 768, jb));
    const u16x4 w1 = LDQ(min(rb + 96, bot));
    const u16x4 w2 = LDQ(min(rb + 192, bot));
    const u16x4 w3 = LDQ(min(rb + 288, bot));
    const u16x4 w4 = LDQ(min(rb + 384, bot));
    const u16x4 w5 = LDQ(min(rb + 480, bot));
    const u16x4 w6 = LDQ(min(rb + 576, bot));
    const u16x4 w7 = LDQ(min(rb + 672, bot));
    const u16x4 w8 = LDQ(min(rb + 768, bot));
    const u16x4 mu = EMIN(EMIN(EMIN(EMAX(u1, K1), EMAX(u2, K2)),
                                EMIN(EMAX(u3, K3), EMAX(u4, K4))),
                          EMIN(EMIN(EMAX(u5, K5), EMAX(u6, K6)),
                                EMIN(EMAX(u7, K7), EMAX(u8, K8))));
    const u16x4 mw = EMIN(EMIN(EMIN(EMAX(w1, K1), EMAX(w2, K2)),
                                EMIN(EMAX(w3, K3), EMAX(w4, K4))),
                          EMIN(EMIN(EMAX(w5, K5), EMAX(w6, K6)),
                                EMIN(EMAX(w7, K7), EMAX(w8, K8))));
    u16x4 b = EMIN(b0, EMIN(mu, mw));
    unsigned long long bb = __builtin_bit_cast(unsigned long long, b);
    unsigned int blo = (unsigned int)bb, bhi = (unsigned int)(bb >> 32);
    int bm = max(max((int)(blo & 0xFFFFu), (int)(blo >> 16)),
                 max((int)(bhi & 0xFFFFu), (int)(bhi >> 16)));
    int k = 9;
    int au = rb - 768, ad = rb + 768;
    while (k < bm) {
      const unsigned short t1 = (unsigned short)k, t2 = (unsigned short)(k + 1),
                           t3 = (unsigned short)(k + 2), t4 = (unsigned short)(k + 3);
      const u16x4 c1 = {t1, t1, t1, t1}, c2 = {t2, t2, t2, t2},
                  c3 = {t3, t3, t3, t3}, c4 = {t4, t4, t4, t4};
      const u16x4 a1 = LDQ(max(au - 96, jb));
      const u16x4 a2 = LDQ(max(au - 192, jb));
      const u16x4 a3 = LDQ(max(au - 288, jb));
      const u16x4 a4 = LDQ(max(au - 384, jb));
      const u16x4 e1 = LDQ(min(ad + 96, bot));
      const u16x4 e2 = LDQ(min(ad + 192, bot));
      const u16x4 e3 = LDQ(min(ad + 288, bot));
      const u16x4 e4 = LDQ(min(ad + 384, bot));
      const u16x4 t = EMIN(EMIN(EMIN(EMAX(a1, c1), EMAX(a2, c2)),
                                 EMIN(EMAX(a3, c3), EMAX(a4, c4))),
                           EMIN(EMIN(EMAX(e1, c1), EMAX(e2, c2)),
                                 EMIN(EMAX(e3, c3), EMAX(e4, c4))));
      b = EMIN(b, t);
      au -= 384;
      ad += 384;
      k += 4;
      bb = __builtin_bit_cast(unsigned long long, b);
      blo = (unsigned int)bb;
      bhi = (unsigned int)(bb >> 32);
      bm = max(max((int)(blo & 0xFFFFu), (int)(blo >> 16)),
               max((int)(bhi & 0xFFFFu), (int)(bhi >> 16)));
    }
    const unsigned int packed = __builtin_amdgcn_perm(bhi, blo, 0x06040200u);
    *reinterpret_cast<unsigned int*>(&Ds[r * 44 + g * 4]) = packed;
  }
  __syncthreads();

  // ---- row-major shared-align SWAR epilogue: 4 cols x 4 rows per thread ----
  const float wA = 3.17814e-2f, wB = 2.35426e-3f, wC = 1.91126e-4f, wD = 1.35150e-5f;
  const float W4 = 8.0f * wA + 12.0f * wB + 16.0f * wC + 12.0f * wD;

  const int cg = tid & 7;
  const int rg = tid >> 3;
  const int rl0 = rg * 4;
  const int jb2 = cg * 4;
  const size_t obase = (size_t)ch * 65536 + (size_t)(y0 + rl0) * 256 + x0 + cg * 4;

  // center dwords for the 4 output rows
  const unsigned int Dc0 =
      *reinterpret_cast<const unsigned int*>(&Ds[(rl0 + 3) * 44 + jb2 + 4]);
  const unsigned int Dc1 =
      *reinterpret_cast<const unsigned int*>(&Ds[(rl0 + 4) * 44 + jb2 + 4]);
  const unsigned int Dc2 =
      *reinterpret_cast<const unsigned int*>(&Ds[(rl0 + 5) * 44 + jb2 + 4]);
  const unsigned int Dc3 =
      *reinterpret_cast<const unsigned int*>(&Ds[(rl0 + 6) * 44 + jb2 + 4]);
  CPSET(0, Dc0);
  CPSET(1, Dc1);
  CPSET(2, Dc2);
  CPSET(3, Dc3);

  unsigned int aA0 = 0, aB0 = 0, aC0 = 0, aD0 = 0;
  unsigned int aA1 = 0, aB1 = 0, aC1 = 0, aD1 = 0;
  unsigned int aA2 = 0, aB2 = 0, aC2 = 0, aD2 = 0;
  unsigned int aA3 = 0, aB3 = 0, aC3 = 0, aD3 = 0;

  ROWU(0, PT0(0));
  ROWU(1, PT1(0) PT0(1));
  ROWU(2, PT2(0) PT1(1) PT0(2));
  ROWU(3, PT3(0) PT2(1) PT1(2) PT0(3));
  ROWU(4, PT2(0) PT3(1) PT2(2) PT1(3));
  ROWU(5, PT1(0) PT2(1) PT3(2) PT2(3));
  ROWU(6, PT0(0) PT1(1) PT2(2) PT3(3));
  ROWU(7, PT0(1) PT1(2) PT2(3));
  ROWU(8, PT0(2) PT1(3));
  ROWU(9, PT0(3));

  FIN(0, Dc0);
  FIN(1, Dc1);
  FIN(2, Dc2);
  FIN(3, Dc3);
}

extern "C" void kernel_launch(void* const* d_in, const int* in_sizes, int n_in,
                              void* d_out, int out_size, void* d_ws, size_t ws_size,
                              hipStream_t stream) {
  const float* img = (const float*)d_in[0];
  float* out = (float*)d_out;
  unsigned char* Dbuf = (unsigned char*)d_ws;

  const int total = in_sizes[0];  // B*C*H*W
  const int nch = total >> 16;    // B*C (H=W=256)

  k_rowdist<<<dim3(nch * 64), dim3(256), 0, stream>>>(img, Dbuf);
  k_fused<<<dim3(nch * 16), dim3(256), 0, stream>>>(Dbuf, out);
}